// Round 5
// baseline (659.394 us; speedup 1.0000x reference)
//
#include <hip/hip_runtime.h>
#include <cstdint>
#include <cstddef>

#define DEVFN static __device__ __forceinline__

typedef __attribute__((ext_vector_type(4))) float f32x4;
typedef __attribute__((ext_vector_type(8))) __bf16 bf16x8;

typedef __attribute__((address_space(1))) void gvoid;
typedef __attribute__((address_space(3))) void svoid;

DEVFN unsigned short f32_to_bf16_bits(float f) {
  uint32_t u = __builtin_bit_cast(uint32_t, f);
  return (unsigned short)((u + 0x7fffu + ((u >> 16) & 1u)) >> 16);
}
DEVFN float bf16_lo(uint32_t d) { return __builtin_bit_cast(float, d << 16); }
DEVFN float bf16_hi(uint32_t d) { return __builtin_bit_cast(float, d & 0xffff0000u); }
DEVFN uint32_t pack_bf16x2(float lo, float hi) {
  return (uint32_t)f32_to_bf16_bits(lo) | ((uint32_t)f32_to_bf16_bits(hi) << 16);
}

// global -> LDS direct copy, 16B per lane. LDS base must be wave-uniform;
// lane i lands at lds + i*16 bytes.
DEVFN void load_lds16(const void* g, void* l) {
  __builtin_amdgcn_global_load_lds((const gvoid*)g, (svoid*)l, 16, 0, 0);
}

// ---------------- all fp32 -> bf16 conversions + WkT transpose, ONE launch ----------------
// chunk = 8 output elems. Ranges (block-aligned):
//   [0,524288)        query -> qb
//   [524288,557056)   Wq -> Wqb
//   [557056,589824)   Wv -> Wvb
//   [589824,622592)   Wo -> Wob
//   [622592,688128)   W1 -> W1b
//   [688128,753664)   W2 -> W2b
//   [753664,786432)   Wk -> WkT[h][j][d] transpose
__global__ __launch_bounds__(256) void cvt_all(
    const float* __restrict__ q, const float* __restrict__ Wq,
    const float* __restrict__ Wv, const float* __restrict__ Wo,
    const float* __restrict__ W1, const float* __restrict__ W2,
    const float* __restrict__ Wk,
    unsigned short* __restrict__ qb, unsigned short* __restrict__ Wqb,
    unsigned short* __restrict__ Wvb, unsigned short* __restrict__ Wob,
    unsigned short* __restrict__ W1b, unsigned short* __restrict__ W2b,
    unsigned short* __restrict__ WkT) {
  int i = (int)(blockIdx.x * 256 + threadIdx.x);
  if (i >= 753664) {  // WkT transpose tail (wave-uniform branch; ranges block-aligned)
    int off = i - 753664;
    int oidx = off * 8;
    int d0 = oidx & 63;
    int j = (oidx >> 6) & 511;
    int h = oidx >> 15;
    union { unsigned short s[8]; uint4 v; } o;
#pragma unroll
    for (int t = 0; t < 8; ++t)
      o.s[t] = f32_to_bf16_bits(Wk[(size_t)((h << 6) + d0 + t) * 512 + j]);
    ((uint4*)WkT)[off] = o.v;
    return;
  }
  const float* src;
  unsigned short* dst;
  int off;
  if (i < 524288)      { src = q;  dst = qb;  off = i; }
  else if (i < 557056) { src = Wq; dst = Wqb; off = i - 524288; }
  else if (i < 589824) { src = Wv; dst = Wvb; off = i - 557056; }
  else if (i < 622592) { src = Wo; dst = Wob; off = i - 589824; }
  else if (i < 688128) { src = W1; dst = W1b; off = i - 622592; }
  else                 { src = W2; dst = W2b; off = i - 688128; }
  const float4* p = (const float4*)src;
  float4 a = p[2 * off], b = p[2 * off + 1];
  union { unsigned short s[8]; uint4 v; } o;
  o.s[0] = f32_to_bf16_bits(a.x); o.s[1] = f32_to_bf16_bits(a.y);
  o.s[2] = f32_to_bf16_bits(a.z); o.s[3] = f32_to_bf16_bits(a.w);
  o.s[4] = f32_to_bf16_bits(b.x); o.s[5] = f32_to_bf16_bits(b.y);
  o.s[6] = f32_to_bf16_bits(b.z); o.s[7] = f32_to_bf16_bits(b.w);
  ((uint4*)dst)[off] = o.v;
}

// ---------------- bf16 MFMA GEMM, B given transposed (Bt[n][k]) ----------------
// C[m][n] = sum_k A[m][k]*Bt[n][k] (+bias[n]) (+res[m][n]) (relu) -> bf16|f32
// 4 waves in 2x2; wave tile (BM/2) x (BN/2); BK=32.
template<int BM, int BN, bool OUT_BF16, bool RELU, bool ADD_RES>
__global__ __launch_bounds__(256)
void gemm_bt(const unsigned short* __restrict__ A, int lda, long long zA,
             const unsigned short* __restrict__ Bt, int ldb, long long zB,
             void* __restrict__ Cv, int ldc, long long zC,
             const float* __restrict__ bias, int zBias,
             const float* __restrict__ res, int ldres,
             int K) {
  constexpr int MT = BM / 32;  // mfma row-tiles per wave
  constexpr int NT = BN / 32;  // mfma col-tiles per wave
  constexpr int AQ = BM / 64;  // A staging issues per wave (1KB each)
  constexpr int BQ = BN / 64;
  __shared__ __align__(16) unsigned short As[BM * 32];
  __shared__ __align__(16) unsigned short Bs[BN * 32];

  const int tid = (int)threadIdx.x;
  const int lane = tid & 63;
  const int w = tid >> 6;
  const int wm = w >> 1;
  const int wn = w & 1;
  const int m0 = (int)blockIdx.y * BM;
  const int n0 = (int)blockIdx.x * BN;
  const long long z = (long long)blockIdx.z;

  A += z * zA;
  Bt += z * zB;
  const float* biasz = bias ? (bias + z * zBias) : nullptr;

  f32x4 acc[MT][NT];
#pragma unroll
  for (int i = 0; i < MT; ++i)
#pragma unroll
    for (int j = 0; j < NT; ++j) acc[i][j] = f32x4{0.f, 0.f, 0.f, 0.f};

  // staging: issue q covers bytes [q*4096 + w*1024, +1024); row = o/64, kcol = (o&63)/2
  int rA[AQ], cA[AQ], rB[BQ], cB[BQ];
#pragma unroll
  for (int q = 0; q < AQ; ++q) {
    const int o = q * 4096 + w * 1024 + lane * 16;
    rA[q] = o >> 6; cA[q] = (o & 63) >> 1;
  }
#pragma unroll
  for (int q = 0; q < BQ; ++q) {
    const int o = q * 4096 + w * 1024 + lane * 16;
    rB[q] = o >> 6; cB[q] = (o & 63) >> 1;
  }

  const int kIters = K / 32;
  for (int kt = 0; kt < kIters; ++kt) {
    const int k0 = kt * 32;
    __syncthreads();
#pragma unroll
    for (int q = 0; q < AQ; ++q)
      load_lds16(A + (size_t)(m0 + rA[q]) * lda + (k0 + cA[q]), As + q * 2048 + w * 512);
#pragma unroll
    for (int q = 0; q < BQ; ++q)
      load_lds16(Bt + (size_t)(n0 + rB[q]) * ldb + (k0 + cB[q]), Bs + q * 2048 + w * 512);
    asm volatile("s_waitcnt vmcnt(0)" ::: "memory");
    __syncthreads();

    const int fr = lane & 15;
    const int kq = lane >> 4;
    bf16x8 af[MT], bf[NT];
#pragma unroll
    for (int i = 0; i < MT; ++i) {
      const int m = wm * (BM / 2) + i * 16 + fr;
      af[i] = __builtin_bit_cast(bf16x8, *(const uint4*)(As + m * 32 + kq * 8));
    }
#pragma unroll
    for (int j = 0; j < NT; ++j) {
      const int n = wn * (BN / 2) + j * 16 + fr;
      bf[j] = __builtin_bit_cast(bf16x8, *(const uint4*)(Bs + n * 32 + kq * 8));
    }
#pragma unroll
    for (int i = 0; i < MT; ++i)
#pragma unroll
      for (int j = 0; j < NT; ++j)
        acc[i][j] = __builtin_amdgcn_mfma_f32_16x16x32_bf16(af[i], bf[j], acc[i][j], 0, 0, 0);
  }

  // epilogue: C/D layout col=lane&15, row=(lane>>4)*4+reg
  const int fr = lane & 15;
  const int rq = lane >> 4;
  unsigned short* Cb = (unsigned short*)Cv + z * zC;
  float* Cf = (float*)Cv + z * zC;
#pragma unroll
  for (int i = 0; i < MT; ++i) {
    const int rbase = m0 + wm * (BM / 2) + i * 16 + rq * 4;
#pragma unroll
    for (int j = 0; j < NT; ++j) {
      const int col = n0 + wn * (BN / 2) + j * 16 + fr;
      const float bvv = biasz ? biasz[col] : 0.f;
#pragma unroll
      for (int r = 0; r < 4; ++r) {
        float v = acc[i][j][r] + bvv;
        if (ADD_RES) v += res[(size_t)(rbase + r) * ldres + col];
        if (RELU) v = fmaxf(v, 0.f);
        if (OUT_BF16) Cb[(size_t)(rbase + r) * ldc + col] = f32_to_bf16_bits(v);
        else Cf[(size_t)(rbase + r) * ldc + col] = v;
      }
    }
  }
}

// ---------------- fused scores/softmax/vbar (in-place U -> vbar), v8 ----------------
// Wave = 2 tokens; block = 4 waves = 8 tokens; 1024 blocks.
// v7 post-mortem: WRITE_SIZE 65.5->121.8 MB revealed scratch spill — the fully
// unrolled PV hoisted 16 V float4 (64 regs) against acc[8][8] (64 regs) past
// the launch_bounds cap of 128. v8 splits PV into 4 SEQUENTIAL passes
// (token x column-half), each acc[8][4] + 8 prefetched V float4 = ~72 live.
// #pragma unroll 1 on both outer loops prevents re-interleaving.
// Scores phase unchanged from v7 (MFMA on direct-global operands).
__global__ __launch_bounds__(256, 4) void attn_kernel(const float* __restrict__ key,
                                                      const float* __restrict__ value,
                                                      unsigned short* __restrict__ U) {
  __shared__ float att_lds[4][128];  // [wave][tok*64 + c*8 + h]
  const int lane = (int)threadIdx.x & 63;
  const int w = (int)threadIdx.x >> 6;
  const int n0 = (int)blockIdx.x * 8 + w * 2;  // wave owns tokens n0, n0+1
  const int fr = lane & 15;
  const int kq = lane >> 4;
  const int tok = fr >> 3;  // which of the 2 tokens this lane's A/B row belongs to
  const int hc = fr & 7;    // head index (A) / cache-row index (B)

  // A: U[(n0+tok), hc*512 + k]  (bf16); B: key[(n0+tok)*8 + hc, k] (f32)
  const unsigned short* Ap = U + (size_t)(n0 + tok) * 4096 + hc * 512 + kq * 8;
  const float* Kp = key + ((size_t)(n0 + tok) * 8 + hc) * 512 + kq * 8;

  f32x4 sc = f32x4{0.f, 0.f, 0.f, 0.f};
  uint4 aC = *(const uint4*)Ap;
  float4 k0C = *(const float4*)Kp;
  float4 k1C = *(const float4*)(Kp + 4);
#pragma unroll
  for (int kt = 0; kt < 16; ++kt) {
    uint4 aN = aC;
    float4 k0N = k0C, k1N = k1C;
    if (kt + 1 < 16) {
      aN = *(const uint4*)(Ap + (kt + 1) * 32);
      k0N = *(const float4*)(Kp + (kt + 1) * 32);
      k1N = *(const float4*)(Kp + (kt + 1) * 32 + 4);
    }
    union { uint32_t u[4]; bf16x8 v; } bk;
    bk.u[0] = pack_bf16x2(k0C.x, k0C.y);
    bk.u[1] = pack_bf16x2(k0C.z, k0C.w);
    bk.u[2] = pack_bf16x2(k1C.x, k1C.y);
    bk.u[3] = pack_bf16x2(k1C.z, k1C.w);
    sc = __builtin_amdgcn_mfma_f32_16x16x32_bf16(
        __builtin_bit_cast(bf16x8, aC), bk.v, sc, 0, 0, 0);
    aC = aN; k0C = k0N; k1C = k1N;
  }

  // softmax per C-row over its 8-lane column half. reg r -> row = kq*4 + r,
  // col = fr. Valid iff (row>>3) == (col>>3) i.e. (kq>>1) == (fr>>3).
  float av[4];
#pragma unroll
  for (int r = 0; r < 4; ++r) {
    const float v = sc[r] * 0.125f;  // 1/sqrt(64)
    float m = v;
#pragma unroll
    for (int off = 1; off < 8; off <<= 1) m = fmaxf(m, __shfl_xor(m, off, 64));
    const float e = __expf(v - m);
    float s = e;
#pragma unroll
    for (int off = 1; off < 8; off <<= 1) s += __shfl_xor(s, off, 64);
    av[r] = e / s;
  }

  // att -> LDS (wave-internal; same wave reads it back, no barrier needed).
  // av[0..3] are heads (kq&1)*4 .. +3 for (tok', c) = (fr>>3, fr&7).
  if ((kq >> 1) == (fr >> 3)) {
    *(float4*)&att_lds[w][(fr >> 3) * 64 + (fr & 7) * 8 + (kq & 1) * 4] =
        make_float4(av[0], av[1], av[2], av[3]);
  }

  // PV: 4 sequential low-pressure passes (token x column-half); acc[8][4].
#pragma unroll 1
  for (int t = 0; t < 2; ++t) {
    const float* vbase = value + (size_t)(n0 + t) * 4096;
    unsigned short* Uw = U + (size_t)(n0 + t) * 4096;
#pragma unroll 1
    for (int half = 0; half < 2; ++half) {
      float4 vv[8];
#pragma unroll
      for (int c = 0; c < 8; ++c)
        vv[c] = *(const float4*)(vbase + c * 512 + half * 256 + 4 * lane);
      float acc[8][4];
#pragma unroll
      for (int h = 0; h < 8; ++h)
#pragma unroll
        for (int e = 0; e < 4; ++e) acc[h][e] = 0.f;
#pragma unroll
      for (int c = 0; c < 8; ++c) {
        const float4 a0 = *(const float4*)&att_lds[w][t * 64 + c * 8 + 0];
        const float4 a1 = *(const float4*)&att_lds[w][t * 64 + c * 8 + 4];
        const float ah[8] = {a0.x, a0.y, a0.z, a0.w, a1.x, a1.y, a1.z, a1.w};
#pragma unroll
        for (int h = 0; h < 8; ++h) {
          acc[h][0] += ah[h] * vv[c].x; acc[h][1] += ah[h] * vv[c].y;
          acc[h][2] += ah[h] * vv[c].z; acc[h][3] += ah[h] * vv[c].w;
        }
      }
#pragma unroll
      for (int h = 0; h < 8; ++h) {
        uint2 o;
        o.x = pack_bf16x2(acc[h][0], acc[h][1]);
        o.y = pack_bf16x2(acc[h][2], acc[h][3]);
        *(uint2*)(Uw + h * 512 + half * 256 + 4 * lane) = o;
      }
    }
  }
}

// ---------------- LayerNorm over rows of 512; wave per row ----------------
__global__ __launch_bounds__(256) void ln_kernel(const float* __restrict__ in,
                                                 const float* __restrict__ g,
                                                 const float* __restrict__ b,
                                                 float* __restrict__ outf,
                                                 unsigned short* __restrict__ outb) {
  const int lane = (int)threadIdx.x & 63;
  const size_t row = (size_t)blockIdx.x * 4 + (threadIdx.x >> 6);
  const int col = lane * 8;
  const float* x = in + row * 512;
  float4 a0 = *(const float4*)(x + col);
  float4 a1 = *(const float4*)(x + col + 4);
  float v[8] = {a0.x, a0.y, a0.z, a0.w, a1.x, a1.y, a1.z, a1.w};
  float s = 0.f, sq = 0.f;
#pragma unroll
  for (int t = 0; t < 8; ++t) { s += v[t]; sq += v[t] * v[t]; }
#pragma unroll
  for (int off = 32; off > 0; off >>= 1) {
    s += __shfl_xor(s, off, 64);
    sq += __shfl_xor(sq, off, 64);
  }
  const float mean = s * (1.f / 512.f);
  const float var = sq * (1.f / 512.f) - mean * mean;
  const float rstd = rsqrtf(var + 1e-5f);
  float o[8];
#pragma unroll
  for (int t = 0; t < 8; ++t) o[t] = (v[t] - mean) * rstd * g[col + t] + b[col + t];
  if (outf) {
    *(float4*)(outf + row * 512 + col) = make_float4(o[0], o[1], o[2], o[3]);
    *(float4*)(outf + row * 512 + col + 4) = make_float4(o[4], o[5], o[6], o[7]);
  }
  if (outb) {
    union { unsigned short s_[8]; uint4 v_; } u;
#pragma unroll
    for (int t = 0; t < 8; ++t) u.s_[t] = f32_to_bf16_bits(o[t]);
    *(uint4*)(outb + row * 512 + col) = u.v_;
  }
}

extern "C" void kernel_launch(void* const* d_in, const int* in_sizes, int n_in,
                              void* d_out, int out_size, void* d_ws, size_t ws_size,
                              hipStream_t stream) {
  const float* query = (const float*)d_in[0];
  const float* key   = (const float*)d_in[1];
  const float* value = (const float*)d_in[2];
  const float* Wq = (const float*)d_in[3];
  const float* bq = (const float*)d_in[4];
  const float* Wk = (const float*)d_in[5];
  // bk (d_in[6]) cancels exactly in the softmax -> unused
  const float* Wv = (const float*)d_in[7];
  const float* bv = (const float*)d_in[8];
  const float* Wo = (const float*)d_in[9];
  const float* bo = (const float*)d_in[10];
  const float* ln1g = (const float*)d_in[11];
  const float* ln1b = (const float*)d_in[12];
  const float* W1 = (const float*)d_in[13];
  const float* b1 = (const float*)d_in[14];
  const float* W2 = (const float*)d_in[15];
  const float* b2 = (const float*)d_in[16];
  const float* ln2g = (const float*)d_in[17];
  const float* ln2b = (const float*)d_in[18];
  float* out = (float*)d_out;

  char* ws = (char*)d_ws;
  size_t off = 0;
  auto alloc = [&](size_t bytes) -> void* {
    off = (off + 255) & ~(size_t)255;
    void* p = ws + off;
    off += bytes;
    return p;
  };

  const int N = 8192;  // tokens = F*B
  unsigned short* qb   = (unsigned short*)alloc((size_t)N * 512 * 2);
  unsigned short* Wqb  = (unsigned short*)alloc(512 * 512 * 2);
  unsigned short* Wvb  = (unsigned short*)alloc(512 * 512 * 2);
  unsigned short* Wob  = (unsigned short*)alloc(512 * 512 * 2);
  unsigned short* W1b  = (unsigned short*)alloc(1024 * 512 * 2);
  unsigned short* W2b  = (unsigned short*)alloc(512 * 1024 * 2);
  unsigned short* WkT  = (unsigned short*)alloc(8 * 512 * 64 * 2);
  unsigned short* Qp   = (unsigned short*)alloc((size_t)N * 512 * 2);   // later reused as x
  unsigned short* U    = (unsigned short*)alloc((size_t)N * 4096 * 2);  // U, then vbar in-place
  float*          h1pre= (float*)alloc((size_t)N * 512 * 4);            // later reused as o2pre
  unsigned short* h1b  = (unsigned short*)alloc((size_t)N * 512 * 2);
  float*          h1f  = (float*)alloc((size_t)N * 512 * 4);
  unsigned short* mid  = (unsigned short*)alloc((size_t)N * 1024 * 2);
  unsigned short* x    = Qp;       // reuse (Qp dead after U-GEMM)
  float*          o2pre= h1pre;    // reuse (raw pre-LN1 dead after LN1)
  (void)ws_size; (void)in_sizes; (void)n_in; (void)out_size;

  dim3 blk(256);
  // all conversions + WkT transpose in one launch
  cvt_all<<<3072, blk, 0, stream>>>(query, Wq, Wv, Wo, W1, W2, Wk,
                                    qb, Wqb, Wvb, Wob, W1b, W2b, WkT);

  // Qp = qb @ Wq^T + bq            [8192 x 512], bf16   (64x64 tiles, 1024 blocks)
  gemm_bt<64, 64, true, false, false><<<dim3(8, 128, 1), blk, 0, stream>>>(
      qb, 512, 0, Wqb, 512, 0, Qp, 512, 0, bq, 0, nullptr, 0, 512);
  // U[n, h*512+j] = Qp[n, h*64:..] @ WkT[h]   (K=64 per head, grid.z = head; 2048 blocks)
  gemm_bt<128, 128, true, false, false><<<dim3(4, 64, 8), blk, 0, stream>>>(
      Qp, 512, 64, WkT, 64, 32768, U, 4096, 512, nullptr, 0, nullptr, 0, 64);
  // scores + softmax + vbar: wave = 2 tokens, block = 8 tokens (1024 blocks)
  attn_kernel<<<1024, blk, 0, stream>>>(key, value, U);
  // x[n, h*64+d] = vbar[n,h,:] @ Wv_head^T + bv_head   (N=64 per head; 1024 blocks)
  gemm_bt<64, 64, true, false, false><<<dim3(1, 128, 8), blk, 0, stream>>>(
      U, 4096, 512, Wvb, 512, 32768, x, 512, 64, bv, 64, nullptr, 0, 512);
  // h1pre = x @ Wo^T + bo + query   (fp32; 1024 blocks)
  gemm_bt<64, 64, false, false, true><<<dim3(8, 128, 1), blk, 0, stream>>>(
      x, 512, 0, Wob, 512, 0, h1pre, 512, 0, bo, 0, query, 512, 512);
  // h1 = LN(h1pre) -> h1f (fp32 residual) + h1b (bf16 GEMM input)
  ln_kernel<<<2048, blk, 0, stream>>>(h1pre, ln1g, ln1b, h1f, h1b);
  // mid = relu(h1 @ W1^T + b1)      [8192 x 1024], bf16  (2048 blocks)
  gemm_bt<64, 64, true, true, false><<<dim3(16, 128, 1), blk, 0, stream>>>(
      h1b, 512, 0, W1b, 512, 0, mid, 1024, 0, b1, 0, nullptr, 0, 512);
  // o2pre = mid @ W2^T + b2 + h1    (fp32; 1024 blocks)
  gemm_bt<64, 64, false, false, true><<<dim3(8, 128, 1), blk, 0, stream>>>(
      mid, 1024, 0, W2b, 1024, 0, o2pre, 512, 0, b2, 0, h1f, 512, 1024);
  // out = LN(o2pre)
  ln_kernel<<<2048, blk, 0, stream>>>(o2pre, ln2g, ln2b, out, nullptr);
}

// Round 6
// 485.245 us; speedup vs baseline: 1.3589x; 1.3589x over previous
//
#include <hip/hip_runtime.h>
#include <cstdint>
#include <cstddef>

#define DEVFN static __device__ __forceinline__

typedef __attribute__((ext_vector_type(4))) float f32x4;
typedef __attribute__((ext_vector_type(8))) __bf16 bf16x8;
typedef __attribute__((ext_vector_type(4))) uint32_t u32x4;

typedef __attribute__((address_space(1))) void gvoid;
typedef __attribute__((address_space(3))) void svoid;

DEVFN unsigned short f32_to_bf16_bits(float f) {
  uint32_t u = __builtin_bit_cast(uint32_t, f);
  return (unsigned short)((u + 0x7fffu + ((u >> 16) & 1u)) >> 16);
}
DEVFN float bf16_lo(uint32_t d) { return __builtin_bit_cast(float, d << 16); }
DEVFN float bf16_hi(uint32_t d) { return __builtin_bit_cast(float, d & 0xffff0000u); }
DEVFN uint32_t pack_bf16x2(float lo, float hi) {
  return (uint32_t)f32_to_bf16_bits(lo) | ((uint32_t)f32_to_bf16_bits(hi) << 16);
}

// global -> LDS direct copy, 16B per lane. LDS base must be wave-uniform;
// lane i lands at lds + i*16 bytes.
DEVFN void load_lds16(const void* g, void* l) {
  __builtin_amdgcn_global_load_lds((const gvoid*)g, (svoid*)l, 16, 0, 0);
}

// ---------------- all fp32 -> bf16 conversions + WkT transpose, ONE launch ----------------
// chunk = 8 output elems. Ranges (block-aligned):
//   [0,524288)        query -> qb
//   [524288,557056)   Wq -> Wqb
//   [557056,589824)   Wv -> Wvb
//   [589824,622592)   Wo -> Wob
//   [622592,688128)   W1 -> W1b
//   [688128,753664)   W2 -> W2b
//   [753664,786432)   Wk -> WkT[h][j][d] transpose
__global__ __launch_bounds__(256) void cvt_all(
    const float* __restrict__ q, const float* __restrict__ Wq,
    const float* __restrict__ Wv, const float* __restrict__ Wo,
    const float* __restrict__ W1, const float* __restrict__ W2,
    const float* __restrict__ Wk,
    unsigned short* __restrict__ qb, unsigned short* __restrict__ Wqb,
    unsigned short* __restrict__ Wvb, unsigned short* __restrict__ Wob,
    unsigned short* __restrict__ W1b, unsigned short* __restrict__ W2b,
    unsigned short* __restrict__ WkT) {
  int i = (int)(blockIdx.x * 256 + threadIdx.x);
  if (i >= 753664) {  // WkT transpose tail (wave-uniform branch; ranges block-aligned)
    int off = i - 753664;
    int oidx = off * 8;
    int d0 = oidx & 63;
    int j = (oidx >> 6) & 511;
    int h = oidx >> 15;
    union { unsigned short s[8]; uint4 v; } o;
#pragma unroll
    for (int t = 0; t < 8; ++t)
      o.s[t] = f32_to_bf16_bits(Wk[(size_t)((h << 6) + d0 + t) * 512 + j]);
    ((uint4*)WkT)[off] = o.v;
    return;
  }
  const float* src;
  unsigned short* dst;
  int off;
  if (i < 524288)      { src = q;  dst = qb;  off = i; }
  else if (i < 557056) { src = Wq; dst = Wqb; off = i - 524288; }
  else if (i < 589824) { src = Wv; dst = Wvb; off = i - 557056; }
  else if (i < 622592) { src = Wo; dst = Wob; off = i - 589824; }
  else if (i < 688128) { src = W1; dst = W1b; off = i - 622592; }
  else                 { src = W2; dst = W2b; off = i - 688128; }
  const float4* p = (const float4*)src;
  float4 a = p[2 * off], b = p[2 * off + 1];
  union { unsigned short s[8]; uint4 v; } o;
  o.s[0] = f32_to_bf16_bits(a.x); o.s[1] = f32_to_bf16_bits(a.y);
  o.s[2] = f32_to_bf16_bits(a.z); o.s[3] = f32_to_bf16_bits(a.w);
  o.s[4] = f32_to_bf16_bits(b.x); o.s[5] = f32_to_bf16_bits(b.y);
  o.s[6] = f32_to_bf16_bits(b.z); o.s[7] = f32_to_bf16_bits(b.w);
  ((uint4*)dst)[off] = o.v;
}

// ---------------- bf16 MFMA GEMM, B given transposed (Bt[n][k]) ----------------
// C[m][n] = sum_k A[m][k]*Bt[n][k] (+bias[n]) (+res[m][n]) (relu) -> bf16|f32
// 4 waves in 2x2; wave tile (BM/2) x (BN/2); BK=32.
template<int BM, int BN, bool OUT_BF16, bool RELU, bool ADD_RES>
__global__ __launch_bounds__(256)
void gemm_bt(const unsigned short* __restrict__ A, int lda, long long zA,
             const unsigned short* __restrict__ Bt, int ldb, long long zB,
             void* __restrict__ Cv, int ldc, long long zC,
             const float* __restrict__ bias, int zBias,
             const float* __restrict__ res, int ldres,
             int K) {
  constexpr int MT = BM / 32;  // mfma row-tiles per wave
  constexpr int NT = BN / 32;  // mfma col-tiles per wave
  constexpr int AQ = BM / 64;  // A staging issues per wave (1KB each)
  constexpr int BQ = BN / 64;
  __shared__ __align__(16) unsigned short As[BM * 32];
  __shared__ __align__(16) unsigned short Bs[BN * 32];

  const int tid = (int)threadIdx.x;
  const int lane = tid & 63;
  const int w = tid >> 6;
  const int wm = w >> 1;
  const int wn = w & 1;
  const int m0 = (int)blockIdx.y * BM;
  const int n0 = (int)blockIdx.x * BN;
  const long long z = (long long)blockIdx.z;

  A += z * zA;
  Bt += z * zB;
  const float* biasz = bias ? (bias + z * zBias) : nullptr;

  f32x4 acc[MT][NT];
#pragma unroll
  for (int i = 0; i < MT; ++i)
#pragma unroll
    for (int j = 0; j < NT; ++j) acc[i][j] = f32x4{0.f, 0.f, 0.f, 0.f};

  // staging: issue q covers bytes [q*4096 + w*1024, +1024); row = o/64, kcol = (o&63)/2
  int rA[AQ], cA[AQ], rB[BQ], cB[BQ];
#pragma unroll
  for (int q = 0; q < AQ; ++q) {
    const int o = q * 4096 + w * 1024 + lane * 16;
    rA[q] = o >> 6; cA[q] = (o & 63) >> 1;
  }
#pragma unroll
  for (int q = 0; q < BQ; ++q) {
    const int o = q * 4096 + w * 1024 + lane * 16;
    rB[q] = o >> 6; cB[q] = (o & 63) >> 1;
  }

  const int kIters = K / 32;
  for (int kt = 0; kt < kIters; ++kt) {
    const int k0 = kt * 32;
    __syncthreads();
#pragma unroll
    for (int q = 0; q < AQ; ++q)
      load_lds16(A + (size_t)(m0 + rA[q]) * lda + (k0 + cA[q]), As + q * 2048 + w * 512);
#pragma unroll
    for (int q = 0; q < BQ; ++q)
      load_lds16(Bt + (size_t)(n0 + rB[q]) * ldb + (k0 + cB[q]), Bs + q * 2048 + w * 512);
    asm volatile("s_waitcnt vmcnt(0)" ::: "memory");
    __syncthreads();

    const int fr = lane & 15;
    const int kq = lane >> 4;
    bf16x8 af[MT], bf[NT];
#pragma unroll
    for (int i = 0; i < MT; ++i) {
      const int m = wm * (BM / 2) + i * 16 + fr;
      af[i] = __builtin_bit_cast(bf16x8, *(const uint4*)(As + m * 32 + kq * 8));
    }
#pragma unroll
    for (int j = 0; j < NT; ++j) {
      const int n = wn * (BN / 2) + j * 16 + fr;
      bf[j] = __builtin_bit_cast(bf16x8, *(const uint4*)(Bs + n * 32 + kq * 8));
    }
#pragma unroll
    for (int i = 0; i < MT; ++i)
#pragma unroll
      for (int j = 0; j < NT; ++j)
        acc[i][j] = __builtin_amdgcn_mfma_f32_16x16x32_bf16(af[i], bf[j], acc[i][j], 0, 0, 0);
  }

  // epilogue: C/D layout col=lane&15, row=(lane>>4)*4+reg
  const int fr = lane & 15;
  const int rq = lane >> 4;
  unsigned short* Cb = (unsigned short*)Cv + z * zC;
  float* Cf = (float*)Cv + z * zC;
#pragma unroll
  for (int i = 0; i < MT; ++i) {
    const int rbase = m0 + wm * (BM / 2) + i * 16 + rq * 4;
#pragma unroll
    for (int j = 0; j < NT; ++j) {
      const int col = n0 + wn * (BN / 2) + j * 16 + fr;
      const float bvv = biasz ? biasz[col] : 0.f;
#pragma unroll
      for (int r = 0; r < 4; ++r) {
        float v = acc[i][j][r] + bvv;
        if (ADD_RES) v += res[(size_t)(rbase + r) * ldres + col];
        if (RELU) v = fmaxf(v, 0.f);
        if (OUT_BF16) Cb[(size_t)(rbase + r) * ldc + col] = f32_to_bf16_bits(v);
        else Cf[(size_t)(rbase + r) * ldc + col] = v;
      }
    }
  }
}

// ---------------- fused scores/softmax/vbar (in-place U -> vbar), v9 ----------------
// Wave = 2 tokens; block = 4 waves = 8 tokens; 1024 blocks.
// v8 post-mortem: VGPR_Count=64 under launch_bounds(256,4) + MFMA — the
// unified-file allocator split the 128-reg cap into 64 arch + 64 acc, so a
// ~72-100 live set spilled ~0.9KB/thread through scratch (WRITE_SIZE 342MB).
// v9 fixes: (1) plain launch_bounds(256) — v4/v6 under this bound allocated
// 88/132 VGPR with zero spill; (2) the bk union (memory type-pun in the hot
// scores loop) replaced by ext_vector u32x4 + bit_cast (register-guaranteed);
// (3) keeps v8's 4-pass low-pressure PV (~72 live per pass).
__global__ __launch_bounds__(256) void attn_kernel(const float* __restrict__ key,
                                                   const float* __restrict__ value,
                                                   unsigned short* __restrict__ U) {
  __shared__ float att_lds[4][128];  // [wave][tok*64 + c*8 + h]
  const int lane = (int)threadIdx.x & 63;
  const int w = (int)threadIdx.x >> 6;
  const int n0 = (int)blockIdx.x * 8 + w * 2;  // wave owns tokens n0, n0+1
  const int fr = lane & 15;
  const int kq = lane >> 4;
  const int tok = fr >> 3;  // which of the 2 tokens this lane's A/B row belongs to
  const int hc = fr & 7;    // head index (A) / cache-row index (B)

  // A: U[(n0+tok), hc*512 + k]  (bf16); B: key[(n0+tok)*8 + hc, k] (f32)
  const unsigned short* Ap = U + (size_t)(n0 + tok) * 4096 + hc * 512 + kq * 8;
  const float* Kp = key + ((size_t)(n0 + tok) * 8 + hc) * 512 + kq * 8;

  f32x4 sc = f32x4{0.f, 0.f, 0.f, 0.f};
  uint4 aC = *(const uint4*)Ap;
  float4 k0C = *(const float4*)Kp;
  float4 k1C = *(const float4*)(Kp + 4);
#pragma unroll
  for (int kt = 0; kt < 16; ++kt) {
    uint4 aN = aC;
    float4 k0N = k0C, k1N = k1C;
    if (kt + 1 < 16) {
      aN = *(const uint4*)(Ap + (kt + 1) * 32);
      k0N = *(const float4*)(Kp + (kt + 1) * 32);
      k1N = *(const float4*)(Kp + (kt + 1) * 32 + 4);
    }
    u32x4 bk;
    bk[0] = pack_bf16x2(k0C.x, k0C.y);
    bk[1] = pack_bf16x2(k0C.z, k0C.w);
    bk[2] = pack_bf16x2(k1C.x, k1C.y);
    bk[3] = pack_bf16x2(k1C.z, k1C.w);
    sc = __builtin_amdgcn_mfma_f32_16x16x32_bf16(
        __builtin_bit_cast(bf16x8, aC), __builtin_bit_cast(bf16x8, bk), sc, 0, 0, 0);
    aC = aN; k0C = k0N; k1C = k1N;
  }

  // softmax per C-row over its 8-lane column half. reg r -> row = kq*4 + r,
  // col = fr. Valid iff (row>>3) == (col>>3) i.e. (kq>>1) == (fr>>3).
  float av[4];
#pragma unroll
  for (int r = 0; r < 4; ++r) {
    const float v = sc[r] * 0.125f;  // 1/sqrt(64)
    float m = v;
#pragma unroll
    for (int off = 1; off < 8; off <<= 1) m = fmaxf(m, __shfl_xor(m, off, 64));
    const float e = __expf(v - m);
    float s = e;
#pragma unroll
    for (int off = 1; off < 8; off <<= 1) s += __shfl_xor(s, off, 64);
    av[r] = e / s;
  }

  // att -> LDS (wave-internal; same wave reads it back, no barrier needed).
  // av[0..3] are heads (kq&1)*4 .. +3 for (tok', c) = (fr>>3, fr&7).
  if ((kq >> 1) == (fr >> 3)) {
    *(float4*)&att_lds[w][(fr >> 3) * 64 + (fr & 7) * 8 + (kq & 1) * 4] =
        make_float4(av[0], av[1], av[2], av[3]);
  }

  // PV: 4 sequential low-pressure passes (token x column-half); acc[8][4].
#pragma unroll 1
  for (int t = 0; t < 2; ++t) {
    const float* vbase = value + (size_t)(n0 + t) * 4096;
    unsigned short* Uw = U + (size_t)(n0 + t) * 4096;
#pragma unroll 1
    for (int half = 0; half < 2; ++half) {
      float4 vv[8];
#pragma unroll
      for (int c = 0; c < 8; ++c)
        vv[c] = *(const float4*)(vbase + c * 512 + half * 256 + 4 * lane);
      float acc[8][4];
#pragma unroll
      for (int h = 0; h < 8; ++h)
#pragma unroll
        for (int e = 0; e < 4; ++e) acc[h][e] = 0.f;
#pragma unroll
      for (int c = 0; c < 8; ++c) {
        const float4 a0 = *(const float4*)&att_lds[w][t * 64 + c * 8 + 0];
        const float4 a1 = *(const float4*)&att_lds[w][t * 64 + c * 8 + 4];
        const float ah[8] = {a0.x, a0.y, a0.z, a0.w, a1.x, a1.y, a1.z, a1.w};
#pragma unroll
        for (int h = 0; h < 8; ++h) {
          acc[h][0] += ah[h] * vv[c].x; acc[h][1] += ah[h] * vv[c].y;
          acc[h][2] += ah[h] * vv[c].z; acc[h][3] += ah[h] * vv[c].w;
        }
      }
#pragma unroll
      for (int h = 0; h < 8; ++h) {
        uint2 o;
        o.x = pack_bf16x2(acc[h][0], acc[h][1]);
        o.y = pack_bf16x2(acc[h][2], acc[h][3]);
        *(uint2*)(Uw + h * 512 + half * 256 + 4 * lane) = o;
      }
    }
  }
}

// ---------------- LayerNorm over rows of 512; wave per row ----------------
__global__ __launch_bounds__(256) void ln_kernel(const float* __restrict__ in,
                                                 const float* __restrict__ g,
                                                 const float* __restrict__ b,
                                                 float* __restrict__ outf,
                                                 unsigned short* __restrict__ outb) {
  const int lane = (int)threadIdx.x & 63;
  const size_t row = (size_t)blockIdx.x * 4 + (threadIdx.x >> 6);
  const int col = lane * 8;
  const float* x = in + row * 512;
  float4 a0 = *(const float4*)(x + col);
  float4 a1 = *(const float4*)(x + col + 4);
  float v[8] = {a0.x, a0.y, a0.z, a0.w, a1.x, a1.y, a1.z, a1.w};
  float s = 0.f, sq = 0.f;
#pragma unroll
  for (int t = 0; t < 8; ++t) { s += v[t]; sq += v[t] * v[t]; }
#pragma unroll
  for (int off = 32; off > 0; off >>= 1) {
    s += __shfl_xor(s, off, 64);
    sq += __shfl_xor(sq, off, 64);
  }
  const float mean = s * (1.f / 512.f);
  const float var = sq * (1.f / 512.f) - mean * mean;
  const float rstd = rsqrtf(var + 1e-5f);
  float o[8];
#pragma unroll
  for (int t = 0; t < 8; ++t) o[t] = (v[t] - mean) * rstd * g[col + t] + b[col + t];
  if (outf) {
    *(float4*)(outf + row * 512 + col) = make_float4(o[0], o[1], o[2], o[3]);
    *(float4*)(outf + row * 512 + col + 4) = make_float4(o[4], o[5], o[6], o[7]);
  }
  if (outb) {
    union { unsigned short s_[8]; uint4 v_; } u;
#pragma unroll
    for (int t = 0; t < 8; ++t) u.s_[t] = f32_to_bf16_bits(o[t]);
    *(uint4*)(outb + row * 512 + col) = u.v_;
  }
}

extern "C" void kernel_launch(void* const* d_in, const int* in_sizes, int n_in,
                              void* d_out, int out_size, void* d_ws, size_t ws_size,
                              hipStream_t stream) {
  const float* query = (const float*)d_in[0];
  const float* key   = (const float*)d_in[1];
  const float* value = (const float*)d_in[2];
  const float* Wq = (const float*)d_in[3];
  const float* bq = (const float*)d_in[4];
  const float* Wk = (const float*)d_in[5];
  // bk (d_in[6]) cancels exactly in the softmax -> unused
  const float* Wv = (const float*)d_in[7];
  const float* bv = (const float*)d_in[8];
  const float* Wo = (const float*)d_in[9];
  const float* bo = (const float*)d_in[10];
  const float* ln1g = (const float*)d_in[11];
  const float* ln1b = (const float*)d_in[12];
  const float* W1 = (const float*)d_in[13];
  const float* b1 = (const float*)d_in[14];
  const float* W2 = (const float*)d_in[15];
  const float* b2 = (const float*)d_in[16];
  const float* ln2g = (const float*)d_in[17];
  const float* ln2b = (const float*)d_in[18];
  float* out = (float*)d_out;

  char* ws = (char*)d_ws;
  size_t off = 0;
  auto alloc = [&](size_t bytes) -> void* {
    off = (off + 255) & ~(size_t)255;
    void* p = ws + off;
    off += bytes;
    return p;
  };

  const int N = 8192;  // tokens = F*B
  unsigned short* qb   = (unsigned short*)alloc((size_t)N * 512 * 2);
  unsigned short* Wqb  = (unsigned short*)alloc(512 * 512 * 2);
  unsigned short* Wvb  = (unsigned short*)alloc(512 * 512 * 2);
  unsigned short* Wob  = (unsigned short*)alloc(512 * 512 * 2);
  unsigned short* W1b  = (unsigned short*)alloc(1024 * 512 * 2);
  unsigned short* W2b  = (unsigned short*)alloc(512 * 1024 * 2);
  unsigned short* WkT  = (unsigned short*)alloc(8 * 512 * 64 * 2);
  unsigned short* Qp   = (unsigned short*)alloc((size_t)N * 512 * 2);   // later reused as x
  unsigned short* U    = (unsigned short*)alloc((size_t)N * 4096 * 2);  // U, then vbar in-place
  float*          h1pre= (float*)alloc((size_t)N * 512 * 4);            // later reused as o2pre
  unsigned short* h1b  = (unsigned short*)alloc((size_t)N * 512 * 2);
  float*          h1f  = (float*)alloc((size_t)N * 512 * 4);
  unsigned short* mid  = (unsigned short*)alloc((size_t)N * 1024 * 2);
  unsigned short* x    = Qp;       // reuse (Qp dead after U-GEMM)
  float*          o2pre= h1pre;    // reuse (raw pre-LN1 dead after LN1)
  (void)ws_size; (void)in_sizes; (void)n_in; (void)out_size;

  dim3 blk(256);
  // all conversions + WkT transpose in one launch
  cvt_all<<<3072, blk, 0, stream>>>(query, Wq, Wv, Wo, W1, W2, Wk,
                                    qb, Wqb, Wvb, Wob, W1b, W2b, WkT);

  // Qp = qb @ Wq^T + bq            [8192 x 512], bf16   (64x64 tiles, 1024 blocks)
  gemm_bt<64, 64, true, false, false><<<dim3(8, 128, 1), blk, 0, stream>>>(
      qb, 512, 0, Wqb, 512, 0, Qp, 512, 0, bq, 0, nullptr, 0, 512);
  // U[n, h*512+j] = Qp[n, h*64:..] @ WkT[h]   (K=64 per head, grid.z = head; 2048 blocks)
  gemm_bt<128, 128, true, false, false><<<dim3(4, 64, 8), blk, 0, stream>>>(
      Qp, 512, 64, WkT, 64, 32768, U, 4096, 512, nullptr, 0, nullptr, 0, 64);
  // scores + softmax + vbar: wave = 2 tokens, block = 8 tokens (1024 blocks)
  attn_kernel<<<1024, blk, 0, stream>>>(key, value, U);
  // x[n, h*64+d] = vbar[n,h,:] @ Wv_head^T + bv_head   (N=64 per head; 1024 blocks)
  gemm_bt<64, 64, true, false, false><<<dim3(1, 128, 8), blk, 0, stream>>>(
      U, 4096, 512, Wvb, 512, 32768, x, 512, 64, bv, 64, nullptr, 0, 512);
  // h1pre = x @ Wo^T + bo + query   (fp32; 1024 blocks)
  gemm_bt<64, 64, false, false, true><<<dim3(8, 128, 1), blk, 0, stream>>>(
      x, 512, 0, Wob, 512, 0, h1pre, 512, 0, bo, 0, query, 512, 512);
  // h1 = LN(h1pre) -> h1f (fp32 residual) + h1b (bf16 GEMM input)
  ln_kernel<<<2048, blk, 0, stream>>>(h1pre, ln1g, ln1b, h1f, h1b);
  // mid = relu(h1 @ W1^T + b1)      [8192 x 1024], bf16  (2048 blocks)
  gemm_bt<64, 64, true, true, false><<<dim3(16, 128, 1), blk, 0, stream>>>(
      h1b, 512, 0, W1b, 512, 0, mid, 1024, 0, b1, 0, nullptr, 0, 512);
  // o2pre = mid @ W2^T + b2 + h1    (fp32; 1024 blocks)
  gemm_bt<64, 64, false, false, true><<<dim3(8, 128, 1), blk, 0, stream>>>(
      mid, 1024, 0, W2b, 1024, 0, o2pre, 512, 0, b2, 0, h1f, 512, 1024);
  // out = LN(o2pre)
  ln_kernel<<<2048, blk, 0, stream>>>(o2pre, ln2g, ln2b, out, nullptr);
}